// Round 15
// baseline (506.824 us; speedup 1.0000x reference)
//
#include <hip/hip_runtime.h>
#include <hip/hip_bf16.h>
#include <cstddef>

#define NSTOCK 100
#define LOG2E 1.4426950408889634f

typedef _Float16 f16x8 __attribute__((ext_vector_type(8)));
typedef _Float16 f16x4 __attribute__((ext_vector_type(4)));
typedef float f32x16 __attribute__((ext_vector_type(16)));

static __device__ __forceinline__ float rcpf(float x){ return __builtin_amdgcn_rcpf(x); }
static __device__ __forceinline__ float exp2f_(float x){ return __builtin_amdgcn_exp2f(x); }

// ---------------------------------------------------------------------------
// prep: permuted+scaled weights Wp[480][144]  (round-8 layout, unchanged).
// ---------------------------------------------------------------------------
__global__ void prep_kernel(const float* __restrict__ W_ih,
                            const float* __restrict__ W_hh,
                            const float* __restrict__ b_ih,
                            const float* __restrict__ b_hh,
                            float* __restrict__ Wp) {
    int idx = blockIdx.x * 256 + threadIdx.x;
    if (idx < 480 * 144) {
        int k = idx % 144;
        int p = idx / 144;
        int n = p >> 5, row = p & 31, jjf = row >> 2, type = row & 3;
        int j = n * 8 + (jjf & 1) * 4 + (jjf >> 1);   // < 120
        int g = type * 120 + j;
        float scale = (type == 2) ? 2.f * LOG2E : -LOG2E;
        float v = 0.f;
        if (k < 136)       v = ((k < 16) ? W_ih[g * 16 + k] : W_hh[g * 120 + (k - 16)]) * scale;
        else if (k == 136) v = (b_ih[g] + b_hh[g]) * scale;   // bias col vs B==1
        Wp[idx] = v;
    }
}

// ---------------------------------------------------------------------------
// lstm: TWO-GROUP pipelined block. 100 blocks x 1024 thr (16 waves), 64
// batch rows/block = 2 independent groups of 32 (A: rows n0..+31, B: +32..63).
// The lstm is LATENCY-bound (wall = one block's 128-step chain), so idle CUs
// are free; per step each wave runs GEMM_A -> GEMM_B -> ACT_A -> ACT_B with
// separate accs: GEMM_B (matrix+LDS pipes) overlaps ACT_A (trans pipe), and
// one barrier covers both groups. r14 numerics (absmax 0): x 3-term, h fp16
// 1-term, c f32 in regs, f32 s-epilogue.
// ---------------------------------------------------------------------------
__global__ __launch_bounds__(1024) void lstm_kernel(
        const float* __restrict__ x,
        const float* __restrict__ Wp,
        const float* __restrict__ w_lin,
        const float* __restrict__ b_lin,
        float* __restrict__ s_out) {
    __shared__ __align__(16) _Float16 AHi[2][2][9][64][8];  // [grp][buf][kt][lane][e]
    __shared__ __align__(16) _Float16 ALoX[2][2][64][8];    // x lo part
    __shared__ float sred[30][64];

    const int tid   = threadIdx.x;
    const int lane  = tid & 63;
    const int w     = tid >> 6;        // wave 0..15
    const int l31   = lane & 31;
    const int lhalf = lane >> 5;
    const int n0    = blockIdx.x * 64;

    // ---- persistent weight fragments (waves 0..14) ----
    f16x8 bh[9], bl0;
    if (w < 15) {
        const int p = w * 32 + l31;
#pragma unroll
        for (int kt = 0; kt < 9; ++kt) {
            const float* wp = Wp + p * 144 + kt * 16 + lhalf * 8;
            f16x8 hi, lo;
#pragma unroll
            for (int e = 0; e < 8; ++e) {
                float v = wp[e];
                _Float16 h_ = (_Float16)v;
                hi[e] = h_;
                lo[e] = (_Float16)(v - (float)h_);
            }
            bh[kt] = hi;
            if (kt == 0) bl0 = lo;
        }
    }

    // ---- zero h-region (kt 1..8), both groups, both buffers ----
    {
        f16x8 z;
#pragma unroll
        for (int e = 0; e < 8; ++e) z[e] = (_Float16)0.f;
        for (int ii = tid; ii < 2048; ii += 1024) {
            int g = ii >> 10, bf = (ii >> 9) & 1, kt = 1 + ((ii >> 6) & 7), ln = ii & 63;
            *(f16x8*)&AHi[g][bf][kt][ln][0] = z;
        }
    }
    __syncthreads();

    // ---- x staging geometry (wave 15): lane -> (row bx, half hx) ----
    const int bx = lane >> 1;
    const int hx = lane & 1;
    const int rA = n0 + bx, rB = n0 + 32 + bx;
    const float* xbaseA = x + (size_t)(rA / NSTOCK) * 204800 + (rA % NSTOCK) * 16 + hx * 8;
    const float* xbaseB = x + (size_t)(rB / NSTOCK) * 204800 + (rB % NSTOCK) * 16 + hx * 8;
    if (w == 15) {   // stage x_0 both groups into buf 0
#pragma unroll
        for (int g = 0; g < 2; ++g) {
            const float* xb = g ? xbaseB : xbaseA;
            float4 a0 = *(const float4*)xb;
            float4 a1 = *(const float4*)(xb + 4);
            float vv[8] = {a0.x, a0.y, a0.z, a0.w, a1.x, a1.y, a1.z, a1.w};
            f16x8 hi, lo;
#pragma unroll
            for (int e = 0; e < 8; ++e) {
                _Float16 h_ = (_Float16)vv[e];
                hi[e] = h_; lo[e] = (_Float16)(vv[e] - (float)h_);
            }
            *(f16x8*)&AHi[g][0][0][bx + 32 * hx][0] = hi;
            *(f16x8*)&ALoX[g][0][bx + 32 * hx][0] = lo;
        }
    }
    // ---- bias column: B[k=136][b] = 1.0 for both groups/buffers ----
    if (tid < 128) {
        int g = tid >> 6, buf = (tid >> 5) & 1, b = tid & 31;
        AHi[g][buf][8][32 + b][0] = (_Float16)1.f;
    }
    __syncthreads();

    // ---- h-write constants ----
    const int ktw = 1 + (w >> 1);
    const int lnw = l31 + 32 * (w & 1);
    const int e0  = 4 * lhalf;

    float cregA[4] = {0.f, 0.f, 0.f, 0.f};
    float cregB[4] = {0.f, 0.f, 0.f, 0.f};
    float hlastA[4] = {0.f, 0.f, 0.f, 0.f};
    float hlastB[4] = {0.f, 0.f, 0.f, 0.f};

    for (int t = 0; t < 128; ++t) {
        const int rb = t & 1;
        const int wb = rb ^ 1;
        if (w == 15) {
            // ---- stage x_{t+1} for both groups into write buffer ----
            int tt = (t < 127) ? t + 1 : 127;
#pragma unroll
            for (int g = 0; g < 2; ++g) {
                const float* xp = (g ? xbaseB : xbaseA) + (size_t)tt * 1600;
                float4 a0 = *(const float4*)xp;
                float4 a1 = *(const float4*)(xp + 4);
                float vv[8] = {a0.x, a0.y, a0.z, a0.w, a1.x, a1.y, a1.z, a1.w};
                f16x8 hi, lo;
#pragma unroll
                for (int e = 0; e < 8; ++e) {
                    _Float16 h_ = (_Float16)vv[e];
                    hi[e] = h_; lo[e] = (_Float16)(vv[e] - (float)h_);
                }
                *(f16x8*)&AHi[g][wb][0][bx + 32 * hx][0] = hi;
                *(f16x8*)&ALoX[g][wb][bx + 32 * hx][0] = lo;
            }
        } else {
            // ---- GEMM A (11 MFMA) ----
            f32x16 accA;
#pragma unroll
            for (int r = 0; r < 16; ++r) accA[r] = 0.f;
            {
                f16x8 ah = *(const f16x8*)&AHi[0][rb][0][lane][0];
                f16x8 al = *(const f16x8*)&ALoX[0][rb][lane][0];
                accA = __builtin_amdgcn_mfma_f32_32x32x16_f16(bh[0], ah, accA, 0, 0, 0);
                accA = __builtin_amdgcn_mfma_f32_32x32x16_f16(bh[0], al, accA, 0, 0, 0);
                accA = __builtin_amdgcn_mfma_f32_32x32x16_f16(bl0, ah, accA, 0, 0, 0);
            }
#pragma unroll
            for (int kt = 1; kt < 9; ++kt) {
                f16x8 ah = *(const f16x8*)&AHi[0][rb][kt][lane][0];
                accA = __builtin_amdgcn_mfma_f32_32x32x16_f16(bh[kt], ah, accA, 0, 0, 0);
            }
            // ---- GEMM B (11 MFMA, independent of ACT A) ----
            f32x16 accB;
#pragma unroll
            for (int r = 0; r < 16; ++r) accB[r] = 0.f;
            {
                f16x8 ah = *(const f16x8*)&AHi[1][rb][0][lane][0];
                f16x8 al = *(const f16x8*)&ALoX[1][rb][lane][0];
                accB = __builtin_amdgcn_mfma_f32_32x32x16_f16(bh[0], ah, accB, 0, 0, 0);
                accB = __builtin_amdgcn_mfma_f32_32x32x16_f16(bh[0], al, accB, 0, 0, 0);
                accB = __builtin_amdgcn_mfma_f32_32x32x16_f16(bl0, ah, accB, 0, 0, 0);
            }
#pragma unroll
            for (int kt = 1; kt < 9; ++kt) {
                f16x8 ah = *(const f16x8*)&AHi[1][rb][kt][lane][0];
                accB = __builtin_amdgcn_mfma_f32_32x32x16_f16(bh[kt], ah, accB, 0, 0, 0);
            }
            // ---- ACT A (trans pipe; overlaps accB completion) ----
            {
                f16x4 hi4;
#pragma unroll
                for (int p = 0; p < 4; ++p) {
                    float iv = rcpf(1.f + exp2f_(accA[4 * p + 0]));
                    float fv = rcpf(1.f + exp2f_(accA[4 * p + 1]));
                    float gv = 1.f - 2.f * rcpf(1.f + exp2f_(accA[4 * p + 2]));
                    float ov = rcpf(1.f + exp2f_(accA[4 * p + 3]));
                    float c = fv * cregA[p] + iv * gv;
                    cregA[p] = c;
                    float h = ov * (1.f - 2.f * rcpf(1.f + exp2f_(c * 2.8853900817779268f)));
                    hlastA[p] = h;
                    hi4[p] = (_Float16)h;
                }
                *(f16x4*)&AHi[0][wb][ktw][lnw][e0] = hi4;
            }
            // ---- ACT B ----
            {
                f16x4 hi4;
#pragma unroll
                for (int p = 0; p < 4; ++p) {
                    float iv = rcpf(1.f + exp2f_(accB[4 * p + 0]));
                    float fv = rcpf(1.f + exp2f_(accB[4 * p + 1]));
                    float gv = 1.f - 2.f * rcpf(1.f + exp2f_(accB[4 * p + 2]));
                    float ov = rcpf(1.f + exp2f_(accB[4 * p + 3]));
                    float c = fv * cregB[p] + iv * gv;
                    cregB[p] = c;
                    float h = ov * (1.f - 2.f * rcpf(1.f + exp2f_(c * 2.8853900817779268f)));
                    hlastB[p] = h;
                    hi4[p] = (_Float16)h;
                }
                *(f16x4*)&AHi[1][wb][ktw][lnw][e0] = hi4;
            }
        }
        __syncthreads();
    }

    // ---- s = h_last . w_lin + b_lin  via f32 partials ----
    if (w < 15) {
        const int jb = w * 8 + 4 * lhalf;
        float spA = 0.f, spB = 0.f;
#pragma unroll
        for (int p = 0; p < 4; ++p) {
            spA += w_lin[jb + p] * hlastA[p];
            spB += w_lin[jb + p] * hlastB[p];
        }
        sred[w * 2 + lhalf][l31] = spA;
        sred[w * 2 + lhalf][32 + l31] = spB;
    }
    __syncthreads();
    if (tid < 64) {
        float s = b_lin[0];
#pragma unroll
        for (int r = 0; r < 30; ++r) s += sred[r][tid];
        s_out[n0 + tid] = s;
    }
}

// ---------------------------------------------------------------------------
// rowsum: 64 blocks (b) x 128 thr -> transposed aT[j][b] = s*0.2,
//         cT[j][b] = rowsum*0.2 (tiny; sets up coalesced phat).
// ---------------------------------------------------------------------------
__global__ __launch_bounds__(128) void rowsum_kernel(const float* __restrict__ s,
                                                     float* __restrict__ aT,
                                                     float* __restrict__ cT) {
    __shared__ float sb[NSTOCK];
    const int b = blockIdx.x, tid = threadIdx.x;
    if (tid < NSTOCK) sb[tid] = s[b * NSTOCK + tid];
    __syncthreads();
    if (tid < NSTOCK) {
        float sj = sb[tid];
        float rs = 0.f;
        for (int i2 = 0; i2 < NSTOCK; ++i2) rs += fabsf(sj - sb[i2]);
        aT[tid * 64 + b] = sj * 0.2f;
        cT[tid * 64 + b] = rs * 0.2f;
    }
}

// ---------------------------------------------------------------------------
// phat: 100 blocks (i) x 64 thr (b): fully coalesced reads (aT/cT) and
// writes (fooT16[(i*100+j)*64 + b], fp16).
// ---------------------------------------------------------------------------
__global__ __launch_bounds__(64) void phat_kernel(const float* __restrict__ aT,
                                                  const float* __restrict__ cT,
                                                  _Float16* __restrict__ fooT16) {
    const int i = blockIdx.x, b = threadIdx.x;
    const float sci = (float)(99 - 2 * i);
    float m = -1e30f;
    for (int j = 0; j < NSTOCK; ++j)
        m = fmaxf(m, sci * aT[j * 64 + b] - cT[j * 64 + b]);
    float sum = 0.f;
    for (int j = 0; j < NSTOCK; ++j)
        sum += __expf(sci * aT[j * 64 + b] - cT[j * 64 + b] - m);
    const float inv = 1.f / sum;
    for (int j = 0; j < NSTOCK; ++j) {
        float v = __expf(sci * aT[j * 64 + b] - cT[j * 64 + b] - m) * inv;
        fooT16[(size_t)(i * NSTOCK + j) * 64 + b] = (_Float16)v;
    }
}

// ---------------------------------------------------------------------------
// mlp1: partial sums z2Tp[half][u][b], 8 u per block, fp16 fooT.
// 64 blocks = (u-group of 8, m-half); 8 waves x 625-m chunks; LDS reduce.
// ---------------------------------------------------------------------------
__global__ __launch_bounds__(512) void mlp1_kernel(const _Float16* __restrict__ fooT16,
                                                   const float* __restrict__ W2,
                                                   float* __restrict__ z2Tp) {
    __shared__ float part[8][8][64];
    const int tid = threadIdx.x;
    const int wv = tid >> 6, lane = tid & 63;
    const int ug = blockIdx.x >> 1, half = blockIdx.x & 1;
    const int u0 = ug * 8;
    const int m0 = half * 5000 + wv * 625;
    float a[8];
#pragma unroll
    for (int q = 0; q < 8; ++q) a[q] = 0.f;
    for (int mi = 0; mi < 625; ++mi) {
        int m = m0 + mi;
        float v = (float)fooT16[(size_t)m * 64 + lane];
#pragma unroll
        for (int q = 0; q < 8; ++q)
            a[q] += v * W2[(size_t)(u0 + q) * 10000 + m];
    }
#pragma unroll
    for (int q = 0; q < 8; ++q) part[wv][q][lane] = a[q];
    __syncthreads();
    {
        int q = tid >> 6, b = tid & 63;   // 512 threads = 8 q x 64 b
        float s = 0.f;
#pragma unroll
        for (int w2 = 0; w2 < 8; ++w2) s += part[w2][q][b];
        z2Tp[((size_t)half * 256 + (u0 + q)) * 64 + b] = s;
    }
}

// ---------------------------------------------------------------------------
// mlp2: zs[u] = relu(b2[u] + z2Tp[0][u][b] + z2Tp[1][u][b]);
//       z3[b][v] = sum_u zs[u]*W3[v][u] + b3[v]; out = softmax_v
// ---------------------------------------------------------------------------
__global__ __launch_bounds__(128) void mlp2_kernel(const float* __restrict__ z2Tp,
                                                   const float* __restrict__ b2,
                                                   const float* __restrict__ W3,
                                                   const float* __restrict__ b3,
                                                   float* __restrict__ out) {
    __shared__ float zs[256];
    __shared__ float logits[NSTOCK];
    const int b = blockIdx.x, tid = threadIdx.x;
    for (int u = tid; u < 256; u += 128) {
        float v = b2[u] + z2Tp[(size_t)u * 64 + b] + z2Tp[(size_t)(256 + u) * 64 + b];
        zs[u] = fmaxf(v, 0.f);
    }
    __syncthreads();
    if (tid < NSTOCK) {
        float acc = b3[tid];
        const float* wr = W3 + tid * 256;
        for (int u = 0; u < 256; ++u) acc += zs[u] * wr[u];
        logits[tid] = acc;
    }
    __syncthreads();
    if (tid < NSTOCK) {
        float m = -1e30f;
        for (int j = 0; j < NSTOCK; ++j) m = fmaxf(m, logits[j]);
        float sum = 0.f;
        for (int j = 0; j < NSTOCK; ++j) sum += __expf(logits[j] - m);
        out[b * NSTOCK + tid] = __expf(logits[tid] - m) / sum;
    }
}

// ---------------------------------------------------------------------------
extern "C" void kernel_launch(void* const* d_in, const int* in_sizes, int n_in,
                              void* d_out, int out_size, void* d_ws, size_t ws_size,
                              hipStream_t stream) {
    const float* x     = (const float*)d_in[0];
    const float* W_ih  = (const float*)d_in[1];
    const float* W_hh  = (const float*)d_in[2];
    const float* b_ih  = (const float*)d_in[3];
    const float* b_hh  = (const float*)d_in[4];
    const float* w_lin = (const float*)d_in[5];
    const float* b_lin = (const float*)d_in[6];
    const float* W2    = (const float*)d_in[7];
    const float* b2    = (const float*)d_in[8];
    const float* W3    = (const float*)d_in[9];
    const float* b3    = (const float*)d_in[10];

    float* ws    = (float*)d_ws;
    float* Wp    = ws;                         // 69120
    float* sbuf  = ws + 69600;                 // 6400
    float* aT    = ws + 76000;                 // 6400
    float* cT    = ws + 82400;                 // 6400
    _Float16* fooT16 = (_Float16*)(ws + 88800);// 640000 halves (320000 floats)
    float* z2Tp  = ws + 408800;                // 2*256*64 = 32768
    float* out   = (float*)d_out;

    prep_kernel<<<271, 256, 0, stream>>>(W_ih, W_hh, b_ih, b_hh, Wp);
    lstm_kernel<<<100, 1024, 0, stream>>>(x, Wp, w_lin, b_lin, sbuf);
    rowsum_kernel<<<64, 128, 0, stream>>>(sbuf, aT, cT);
    phat_kernel<<<100, 64, 0, stream>>>(aT, cT, fooT16);
    mlp1_kernel<<<64, 512, 0, stream>>>(fooT16, W2, z2Tp);
    mlp2_kernel<<<64, 128, 0, stream>>>(z2Tp, b2, W3, b3, out);
}

// Round 16
// 244.490 us; speedup vs baseline: 2.0730x; 2.0730x over previous
//
#include <hip/hip_runtime.h>
#include <hip/hip_bf16.h>
#include <cstddef>

#define NSTOCK 100
#define LOG2E 1.4426950408889634f

typedef _Float16 f16x8 __attribute__((ext_vector_type(8)));
typedef _Float16 f16x4 __attribute__((ext_vector_type(4)));
typedef float f32x16 __attribute__((ext_vector_type(16)));

static __device__ __forceinline__ float rcpf(float x){ return __builtin_amdgcn_rcpf(x); }
static __device__ __forceinline__ float exp2f_(float x){ return __builtin_amdgcn_exp2f(x); }

// ---------------------------------------------------------------------------
// prep: permuted+scaled weights Wp[480][144]  (round-8 layout, unchanged).
// slot p = n*32 + row (n=tile 0..14):  type = row&3, jjf = row>>2,
//   j = n*8 + (jjf&1)*4 + (jjf>>1)  -> thread (lhalf,p) owns 4 contiguous j.
// k: 0..15 x feats (W_ih), 16..135 h (W_hh), 136 = bias column, 137..143 0.
// Scale baked: sigmoid rows (i,f,o) * -log2e; tanh row (g) * +2log2e.
// ---------------------------------------------------------------------------
__global__ void prep_kernel(const float* __restrict__ W_ih,
                            const float* __restrict__ W_hh,
                            const float* __restrict__ b_ih,
                            const float* __restrict__ b_hh,
                            float* __restrict__ Wp) {
    int idx = blockIdx.x * 256 + threadIdx.x;
    if (idx < 480 * 144) {
        int k = idx % 144;
        int p = idx / 144;
        int n = p >> 5, row = p & 31, jjf = row >> 2, type = row & 3;
        int j = n * 8 + (jjf & 1) * 4 + (jjf >> 1);   // < 120
        int g = type * 120 + j;
        float scale = (type == 2) ? 2.f * LOG2E : -LOG2E;
        float v = 0.f;
        if (k < 136)       v = ((k < 16) ? W_ih[g * 16 + k] : W_hh[g * 120 + (k - 16)]) * scale;
        else if (k == 136) v = (b_ih[g] + b_hh[g]) * scale;   // bias col vs B==1
        Wp[idx] = v;
    }
}

// ---------------------------------------------------------------------------
// lstm: r14 structure, FULL-fp16 A-operand. 200 blocks x 1024 thr (16 waves,
// 4/SIMD), 32 batch rows/block; wave 15 = x stager; bias k=136.
// Per wave/step: 9 MFMA, 9 ds_read_b128 (r14: 11/10) -- LDS pipe (the
// largest term, 150 reads -> 135) shrinks, and the GEMM loads all 9 frags
// into registers up-front so the reads issue back-to-back under one
// lgkmcnt instead of read-wait-MFMA ping-pong.
// Precision: W fp16 (W_hh fp16 measured absmax 0 in r14), x fp16 (same
// 2^-11 class; r13's fp16-h also measured 0), c f32 in regs, f32 s-epilogue.
// ---------------------------------------------------------------------------
__global__ __launch_bounds__(1024) void lstm_kernel(
        const float* __restrict__ x,
        const float* __restrict__ Wp,
        const float* __restrict__ w_lin,
        const float* __restrict__ b_lin,
        float* __restrict__ s_out) {
    __shared__ __align__(16) _Float16 AHi[2][9][64][8];   // kt0 = x, kt1-8 = h, +bias
    __shared__ float sred[30][32];

    const int tid   = threadIdx.x;
    const int lane  = tid & 63;
    const int w     = tid >> 6;        // wave 0..15
    const int l31   = lane & 31;
    const int lhalf = lane >> 5;
    const int n0    = blockIdx.x * 32;

    // ---- persistent weight fragments (waves 0..14): fp16 ----
    f16x8 bh[9];
    if (w < 15) {
        const int p = w * 32 + l31;
#pragma unroll
        for (int kt = 0; kt < 9; ++kt) {
            const float* wp = Wp + p * 144 + kt * 16 + lhalf * 8;
            f16x8 hi;
#pragma unroll
            for (int e = 0; e < 8; ++e) hi[e] = (_Float16)wp[e];
            bh[kt] = hi;
        }
    }

    // ---- zero h-region (kt 1..8) of both buffers: 1024 threads, 1:1 ----
    {
        f16x8 z;
#pragma unroll
        for (int e = 0; e < 8; ++e) z[e] = (_Float16)0.f;
        int bf = tid >> 9, kt = 1 + ((tid >> 6) & 7), ln = tid & 63;
        *(f16x8*)&AHi[bf][kt][ln][0] = z;
    }
    __syncthreads();

    // ---- x staging geometry (wave 15): lane -> (row bx, half hx) ----
    const int bx = lane >> 1;
    const int hx = lane & 1;
    const int nx  = n0 + bx;
    const int bbx = nx / NSTOCK, ssx = nx % NSTOCK;
    const float* xbase = x + (size_t)bbx * 204800 + ssx * 16 + hx * 8;
    if (w == 15) {   // stage x_0 into buf 0
        float4 a0 = *(const float4*)xbase;
        float4 a1 = *(const float4*)(xbase + 4);
        float vv[8] = {a0.x, a0.y, a0.z, a0.w, a1.x, a1.y, a1.z, a1.w};
        f16x8 hi;
#pragma unroll
        for (int e = 0; e < 8; ++e) hi[e] = (_Float16)vv[e];
        *(f16x8*)&AHi[0][0][bx + 32 * hx][0] = hi;
    }
    // ---- bias column: B[k=136][b] = 1.0, both buffers (kt8, ln 32+b, e 0;
    //      never overwritten: wave-14 h-writes hit kt8 lanes 0..31 only) ----
    if (tid < 64) {
        int buf = tid >> 5, b = tid & 31;
        AHi[buf][8][32 + b][0] = (_Float16)1.f;
    }
    __syncthreads();

    // ---- h-write constants: thread owns j = w*8 + 4*lhalf + p (p=0..3),
    //      batch = l31 -> AHi[wb][1+(w>>1)][l31+32*(w&1)][4*lhalf+p] ----
    const int ktw = 1 + (w >> 1);
    const int lnw = l31 + 32 * (w & 1);
    const int e0  = 4 * lhalf;

    float creg[4] = {0.f, 0.f, 0.f, 0.f};
    float hlast[4] = {0.f, 0.f, 0.f, 0.f};

    for (int t = 0; t < 128; ++t) {
        const int rb = t & 1;
        const int wb = rb ^ 1;
        if (w == 15) {
            // ---- stage x_{t+1} into write buffer ----
            int tt = (t < 127) ? t + 1 : 127;
            const float* xp = xbase + (size_t)tt * 1600;
            float4 a0 = *(const float4*)xp;
            float4 a1 = *(const float4*)(xp + 4);
            float vv[8] = {a0.x, a0.y, a0.z, a0.w, a1.x, a1.y, a1.z, a1.w};
            f16x8 hi;
#pragma unroll
            for (int e = 0; e < 8; ++e) hi[e] = (_Float16)vv[e];
            *(f16x8*)&AHi[wb][0][bx + 32 * hx][0] = hi;
        } else {
            // ---- GEMM: load all 9 frags up-front, then 9 MFMAs ----
            f16x8 afr[9];
#pragma unroll
            for (int kt = 0; kt < 9; ++kt)
                afr[kt] = *(const f16x8*)&AHi[rb][kt][lane][0];
            f32x16 acc;
#pragma unroll
            for (int r = 0; r < 16; ++r) acc[r] = 0.f;
#pragma unroll
            for (int kt = 0; kt < 9; ++kt)
                acc = __builtin_amdgcn_mfma_f32_32x32x16_f16(bh[kt], afr[kt], acc, 0, 0, 0);
            // ---- lane-local activation (scales/sign baked in weights) ----
            f16x4 hi4;
#pragma unroll
            for (int p = 0; p < 4; ++p) {
                float iv = rcpf(1.f + exp2f_(acc[4 * p + 0]));
                float fv = rcpf(1.f + exp2f_(acc[4 * p + 1]));
                float gv = 1.f - 2.f * rcpf(1.f + exp2f_(acc[4 * p + 2]));
                float ov = rcpf(1.f + exp2f_(acc[4 * p + 3]));
                float c = fv * creg[p] + iv * gv;
                creg[p] = c;
                float h = ov * (1.f - 2.f * rcpf(1.f + exp2f_(c * 2.8853900817779268f)));
                hlast[p] = h;
                hi4[p] = (_Float16)h;
            }
            // ---- h-write: one contiguous 8B vector store ----
            *(f16x4*)&AHi[wb][ktw][lnw][e0] = hi4;
        }
        __syncthreads();
    }

    // ---- s = h_last . w_lin + b_lin  via f32 partials (no fp16 error) ----
    if (w < 15) {
        const int jb = w * 8 + 4 * lhalf;
        float sp = 0.f;
#pragma unroll
        for (int p = 0; p < 4; ++p) sp += w_lin[jb + p] * hlast[p];
        sred[w * 2 + lhalf][l31] = sp;
    }
    __syncthreads();
    if (tid < 32) {
        float s = b_lin[0];
#pragma unroll
        for (int r = 0; r < 30; ++r) s += sred[r][tid];
        s_out[n0 + tid] = s;
    }
}

// ---------------------------------------------------------------------------
// phat: 128 blocks = (b, i-half). fooT[m][b] transposed output.
// ---------------------------------------------------------------------------
__global__ __launch_bounds__(128) void phat_kernel(const float* __restrict__ s,
                                                   float* __restrict__ fooT) {
    __shared__ float a[NSTOCK], c[NSTOCK];
    const int b = blockIdx.x >> 1, half = blockIdx.x & 1, tid = threadIdx.x;
    const float* sb = s + b * NSTOCK;
    if (tid < NSTOCK) {
        float sj = sb[tid];
        float rs = 0.f;
        for (int i2 = 0; i2 < NSTOCK; ++i2) rs += fabsf(sj - sb[i2]);
        a[tid] = sj * 0.2f;
        c[tid] = rs * 0.2f;
    }
    __syncthreads();
    if (tid < 50) {
        const int i = half * 50 + tid;
        const float sci = (float)(99 - 2 * i);
        float m = -1e30f;
        for (int j = 0; j < NSTOCK; ++j) m = fmaxf(m, sci * a[j] - c[j]);
        float sum = 0.f;
        for (int j = 0; j < NSTOCK; ++j) sum += __expf(sci * a[j] - c[j] - m);
        const float inv = 1.f / sum;
        for (int j = 0; j < NSTOCK; ++j)
            fooT[(size_t)(i * NSTOCK + j) * 64 + b] = __expf(sci * a[j] - c[j] - m) * inv;
    }
}

// ---------------------------------------------------------------------------
// mlp1: partial sums z2Tp[half][u][b] = sum_{m in half} fooT[m][b]*W2[u][m]
// 128 blocks = (u-group of 4, m-half); 8 waves x 625-m chunks; LDS reduce.
// bias+relu+combine folded into mlp2.
// ---------------------------------------------------------------------------
__global__ __launch_bounds__(512) void mlp1_kernel(const float* __restrict__ fooT,
                                                   const float* __restrict__ W2,
                                                   float* __restrict__ z2Tp) {
    __shared__ float part[8][4][64];
    const int tid = threadIdx.x;
    const int wv = tid >> 6, lane = tid & 63;
    const int ug = blockIdx.x >> 1, half = blockIdx.x & 1;
    const int u0 = ug * 4;
    const int m0 = half * 5000 + wv * 625;
    float a0 = 0.f, a1 = 0.f, a2 = 0.f, a3 = 0.f;
    for (int mi = 0; mi < 625; ++mi) {
        int m = m0 + mi;
        float v = fooT[(size_t)m * 64 + lane];
        a0 += v * W2[(size_t)(u0 + 0) * 10000 + m];
        a1 += v * W2[(size_t)(u0 + 1) * 10000 + m];
        a2 += v * W2[(size_t)(u0 + 2) * 10000 + m];
        a3 += v * W2[(size_t)(u0 + 3) * 10000 + m];
    }
    part[wv][0][lane] = a0; part[wv][1][lane] = a1;
    part[wv][2][lane] = a2; part[wv][3][lane] = a3;
    __syncthreads();
    if (tid < 256) {
        int q = tid >> 6, b = tid & 63;
        float s = 0.f;
#pragma unroll
        for (int w2 = 0; w2 < 8; ++w2) s += part[w2][q][b];
        z2Tp[((size_t)half * 256 + (u0 + q)) * 64 + b] = s;
    }
}

// ---------------------------------------------------------------------------
// mlp2: zs[u] = relu(b2[u] + z2Tp[0][u][b] + z2Tp[1][u][b]);
//       z3[b][v] = sum_u zs[u]*W3[v][u] + b3[v]; out = softmax_v
// ---------------------------------------------------------------------------
__global__ __launch_bounds__(128) void mlp2_kernel(const float* __restrict__ z2Tp,
                                                   const float* __restrict__ b2,
                                                   const float* __restrict__ W3,
                                                   const float* __restrict__ b3,
                                                   float* __restrict__ out) {
    __shared__ float zs[256];
    __shared__ float logits[NSTOCK];
    const int b = blockIdx.x, tid = threadIdx.x;
    for (int u = tid; u < 256; u += 128) {
        float v = b2[u] + z2Tp[(size_t)u * 64 + b] + z2Tp[(size_t)(256 + u) * 64 + b];
        zs[u] = fmaxf(v, 0.f);
    }
    __syncthreads();
    if (tid < NSTOCK) {
        float acc = b3[tid];
        const float* wr = W3 + tid * 256;
        for (int u = 0; u < 256; ++u) acc += zs[u] * wr[u];
        logits[tid] = acc;
    }
    __syncthreads();
    if (tid < NSTOCK) {
        float m = -1e30f;
        for (int j = 0; j < NSTOCK; ++j) m = fmaxf(m, logits[j]);
        float sum = 0.f;
        for (int j = 0; j < NSTOCK; ++j) sum += __expf(logits[j] - m);
        out[b * NSTOCK + tid] = __expf(logits[tid] - m) / sum;
    }
}

// ---------------------------------------------------------------------------
extern "C" void kernel_launch(void* const* d_in, const int* in_sizes, int n_in,
                              void* d_out, int out_size, void* d_ws, size_t ws_size,
                              hipStream_t stream) {
    const float* x     = (const float*)d_in[0];
    const float* W_ih  = (const float*)d_in[1];
    const float* W_hh  = (const float*)d_in[2];
    const float* b_ih  = (const float*)d_in[3];
    const float* b_hh  = (const float*)d_in[4];
    const float* w_lin = (const float*)d_in[5];
    const float* b_lin = (const float*)d_in[6];
    const float* W2    = (const float*)d_in[7];
    const float* b2    = (const float*)d_in[8];
    const float* W3    = (const float*)d_in[9];
    const float* b3    = (const float*)d_in[10];

    float* ws    = (float*)d_ws;
    float* Wp    = ws;                 // 480*144 = 69120
    float* sbuf  = ws + 69600;         // 6400
    float* fooT  = ws + 76000;         // 10000*64 = 640000
    float* z2Tp  = ws + 716000;        // 2*256*64 = 32768
    float* out   = (float*)d_out;

    prep_kernel<<<271, 256, 0, stream>>>(W_ih, W_hh, b_ih, b_hh, Wp);
    lstm_kernel<<<200, 1024, 0, stream>>>(x, Wp, w_lin, b_lin, sbuf);
    phat_kernel<<<128, 128, 0, stream>>>(sbuf, fooT);
    mlp1_kernel<<<128, 512, 0, stream>>>(fooT, W2, z2Tp);
    mlp2_kernel<<<64, 128, 0, stream>>>(z2Tp, b2, W3, b3, out);
}